// Round 16
// baseline (74.960 us; speedup 1.0000x reference)
//
#include <hip/hip_runtime.h>

#define NB 64        // bins
#define HW 65536     // pixels per channel (256*256)
#define NCH 24       // B*C = 8*3
#define SPLIT 8      // segments per channel-image
#define NSLOT 76     // slots = bin + 6, bins -6..69
#define NQ 19        // 19 float4 quad-slots

// w_b(x) = exp(-K*(f-b)^2), f = 63x, K = 2048/3969.
// r16 (= r15 resubmit; r15 failed on infra like r10, which reran clean):
// QUAD-SLOT b128 RMW. Model fitting ALL r9-r14 data: ~15-17cy per DS wave-
// instruction service at the CU-shared LDS unit (+data cycles).
//   r9: 12 instr/px x (2+15) ~ 204 cy/px -> 22us ✓
//   r11 dual-st64: 6 instrs, 2x data each -> ~204 -> null ✓
//   r13 ds_add ~200cy ✓ ; r14 occupancy null (unit CU-shared) ✓
// Lever: fewer instrs x WIDER payload. 16-tap window = 4 ds_read_b128 +
// 4 ds_write_b128 = 8 instr/px -> ~152 cy/px, ~0.75x.
// Window: s0 = min((ni+1)&~3, 60): slots s0..s0+15 cover bins ni-5..ni+5
// for all ni in [0,63] (drop < 1.5e-7), inside the 76-slot array.
// Weights: exact Gaussian recurrence w_{k+1}=w_k*g_k, g_{k+1}=g_k*e^{-2K}
// (2 exps + 32 mults; VALU ~5% busy = free; values in [6e-21,1], f32-safe).
// Banks: addr = q*4096 + tid*16 -> bank (4*tid+e)%32 uniform; 1024B/instr
// = data-path floor, deterministically conflict-free.
// Private per-thread columns: no atomics (r13), no races; same-wave DS
// in-order -> per-pixel RMW RAW-safe.
__global__ __launch_bounds__(256) void chml_hist(const float* __restrict__ pred,
                                                 const float* __restrict__ targ,
                                                 float* __restrict__ part,
                                                 float* __restrict__ out) {
  const int seg = blockIdx.x;   // 0..SPLIT-1
  const int ct  = blockIdx.y;   // 0..2*NCH-1
  const float* src = (ct < NCH) ? (pred + (size_t)ct * HW)
                                : (targ + (size_t)(ct - NCH) * HW);
  const int tid = threadIdx.x;

  if (seg == 0 && ct == 0 && tid == 0) out[0] = 0.0f;  // for chan's atomicAdd

  // issue all 8 global float4 loads first (in flight during LDS init)
  const float4* s4 = (const float4*)(src + (size_t)seg * (HW / SPLIT));
  float4 P[8];
#pragma unroll
  for (int i = 0; i < 8; ++i) P[i] = s4[i * 256 + tid];

  __shared__ float4 H[NQ][256];   // 77824 B -> 2 blocks/CU
  {
    float4* hz = &H[0][0];
#pragma unroll
    for (int i = tid; i < NQ * 256; i += 256)
      hz[i] = make_float4(0.f, 0.f, 0.f, 0.f);
  }
  __syncthreads();

  const float K  = 0.51599899f;      // 2048/3969
  const float E2 = 0.35629502f;      // exp(-2K)

  float4* const hb = &H[0][tid];     // quad stride = 256 float4 = 4096 B

#pragma unroll
  for (int k2 = 0; k2 < 8; ++k2) {
    float4 p = P[k2];
    float pe[4] = {p.x, p.y, p.z, p.w};
#pragma unroll
    for (int e = 0; e < 4; ++e) {
      float f  = pe[e] * 63.0f;
      int   ni = (int)rintf(f);                 // 0..63
      int   s0 = (ni + 1) & ~3;                 // 4-aligned start slot
      s0 = (s0 > 60) ? 60 : s0;                 // fit window in 76 slots
      float u  = f - (float)(s0 - 6);           // tap k: bin s0+k-6,
                                                // w_k = exp(-K (u-k)^2)
      float4* tp = hb + (s0 << 6);              // quad q0 = s0>>2
      // ---- 4 b128 tap reads (latency overlapped by the weight chain)
      float4 t0 = tp[0], t1 = tp[256], t2 = tp[512], t3 = tp[768];
      // ---- exact Gaussian recurrence, 16 taps
      float w = __expf(-K * u * u);             // w_0
      float g = __expf(K * (2.0f * u - 1.0f));  // g_0 = w_1/w_0
      float wk[16];
#pragma unroll
      for (int k = 0; k < 16; ++k) { wk[k] = w; w *= g; g *= E2; }
      t0.x += wk[0];  t0.y += wk[1];  t0.z += wk[2];  t0.w += wk[3];
      t1.x += wk[4];  t1.y += wk[5];  t1.z += wk[6];  t1.w += wk[7];
      t2.x += wk[8];  t2.y += wk[9];  t2.z += wk[10]; t2.w += wk[11];
      t3.x += wk[12]; t3.y += wk[13]; t3.z += wk[14]; t3.w += wk[15];
      // ---- 4 b128 writebacks
      tp[0] = t0; tp[256] = t1; tp[512] = t2; tp[768] = t3;
    }
  }
  __syncthreads();

  // Fold 256 columns -> 1 per slot, float4-wide.
  // Stage 1: 152 threads = 19 quads x 8 col-groups; thread (q,cg) sums
  // float4 over cols [cg*32, cg*32+32), staggered by q for bank spread.
  const int q  = tid >> 3;
  const int cg = tid & 7;
  float4 facc = make_float4(0.f, 0.f, 0.f, 0.f);
  if (tid < NQ * 8) {
#pragma unroll 8
    for (int i = 0; i < 32; ++i) {
      float4 v = H[q][(cg << 5) + ((i + q) & 31)];
      facc.x += v.x; facc.y += v.y; facc.z += v.z; facc.w += v.w;
    }
  }
  __syncthreads();
  float4* S = &H[0][0];          // scratch (H consumed)
  if (tid < NQ * 8) S[tid] = facc;
  __syncthreads();
  // Stage 2: thread q (<19) combines its 8 partials, writes 4 bins.
  if (tid < NQ) {
    float4 a = make_float4(0.f, 0.f, 0.f, 0.f);
#pragma unroll
    for (int j = 0; j < 8; ++j) {
      float4 v = S[(tid << 3) + j];
      a.x += v.x; a.y += v.y; a.z += v.z; a.w += v.w;
    }
    float* dst = part + ((size_t)ct * SPLIT + seg) * NB;
    float av[4] = {a.x, a.y, a.z, a.w};
#pragma unroll
    for (int e2 = 0; e2 < 4; ++e2) {
      int bin = (tid << 2) + e2 - 6;   // slot = 4q+e2, bin = slot-6
      if (bin >= 0 && bin < NB) dst[bin] = av[e2];
    }
  }
}

// Merged tail: per-channel CDF loss, pre-scaled atomicAdd into out.
// 24 blocks x 64 threads (parallel across CUs — r5 lesson). out was zeroed
// by hist block (0,0); stream order makes this race-free.
__global__ __launch_bounds__(64) void chml_chan(const float* __restrict__ part,
                                                float* __restrict__ out) {
  const int c    = blockIdx.x;
  const int lane = threadIdx.x;
  float vp = 0.0f, vt = 0.0f;
#pragma unroll
  for (int s = 0; s < SPLIT; ++s) {
    vp += part[((size_t)c * SPLIT + s) * NB + lane];
    vt += part[((size_t)(c + NCH) * SPLIT + s) * NB + lane];
  }
  // inclusive prefix scan across 64 lanes
#pragma unroll
  for (int off = 1; off < 64; off <<= 1) {
    float up = __shfl_up(vp, off, 64);
    float ut = __shfl_up(vt, off, 64);
    if (lane >= off) { vp += up; vt += ut; }
  }
  float totp = __shfl(vp, 63, 64);
  float tott = __shfl(vt, 63, 64);
  float l = fabsf(vp / (totp + 1e-7f) - vt / (tott + 1e-7f));
#pragma unroll
  for (int off = 32; off >= 1; off >>= 1) l += __shfl_xor(l, off, 64);
  if (lane == 0) atomicAdd(out, l * (1.0f / (float)(NCH * NB)));
}

extern "C" void kernel_launch(void* const* d_in, const int* in_sizes, int n_in,
                              void* d_out, int out_size, void* d_ws, size_t ws_size,
                              hipStream_t stream) {
  const float* pred = (const float*)d_in[0];
  const float* targ = (const float*)d_in[1];
  float* part = (float*)d_ws;        // 48*8*64 floats = 96 KB

  dim3 grid(SPLIT, 2 * NCH);
  chml_hist<<<grid, 256, 0, stream>>>(pred, targ, part, (float*)d_out);
  chml_chan<<<NCH, 64, 0, stream>>>(part, (float*)d_out);
}